// Round 17
// baseline (142.253 us; speedup 1.0000x reference)
//
#include <hip/hip_runtime.h>

#define SEQ    2048
#define DMODEL 1024
#define NHEAD  16
#define DHEAD  64
#define NBATCH 2

typedef __bf16 bf16x8 __attribute__((ext_vector_type(8)));
typedef float f32x16 __attribute__((ext_vector_type(16)));
typedef float f32x8 __attribute__((ext_vector_type(8)));
typedef unsigned short ushort8v __attribute__((ext_vector_type(8)));
typedef unsigned int uint2v __attribute__((ext_vector_type(2)));
typedef int int4v __attribute__((ext_vector_type(4)));

static __device__ __forceinline__ unsigned short f2b(float f){
  unsigned int u = __builtin_bit_cast(unsigned int, f);
  u += 0x7fffu + ((u>>16)&1u);            // RNE to bf16
  return (unsigned short)(u>>16);
}
static __device__ __forceinline__ float b2f(unsigned short h){
  unsigned int u = ((unsigned int)h)<<16;
  return __builtin_bit_cast(float, u);
}
static __device__ __forceinline__ f32x16 mfma32(bf16x8 a, bf16x8 b, f32x16 c){
  return __builtin_amdgcn_mfma_f32_32x32x16_bf16(a,b,c,0,0,0);
}
static __device__ __forceinline__ ushort8v cvt8(const float* p){
  float4 f0 = *(const float4*)p;
  float4 f1 = *(const float4*)(p+4);
  ushort8v r;
  r[0]=f2b(f0.x); r[1]=f2b(f0.y); r[2]=f2b(f0.z); r[3]=f2b(f0.w);
  r[4]=f2b(f1.x); r[5]=f2b(f1.y); r[6]=f2b(f1.z); r[7]=f2b(f1.w);
  return r;
}
#define GLOAD16(g,l) __builtin_amdgcn_global_load_lds( \
    (const __attribute__((address_space(1))) void*)(g), \
    (__attribute__((address_space(3))) void*)(l), 16, 0, 0)

// ---------- pack X (q,k,v) and W (q,k,v,o) fp32 -> bf16 MFMA fragment order ----------
__global__ __launch_bounds__(256) void cvtXW(
    const float* __restrict__ q, const float* __restrict__ k, const float* __restrict__ v,
    const float* __restrict__ Wq, const float* __restrict__ Wk,
    const float* __restrict__ Wv, const float* __restrict__ Wo,
    unsigned short* __restrict__ Xq, unsigned short* __restrict__ Xk, unsigned short* __restrict__ Xv,
    unsigned short* __restrict__ Wp)
{
  const int z = blockIdx.z;
  const int wave = threadIdx.x>>6, lane = threadIdx.x&63;
  const int l31 = lane&31, hi = lane>>5;
  const float* S;
  unsigned short* dst;
  int g;
  if (z < 3){
    S = (z==0)? q : (z==1)? k : v;
    unsigned short* D = (z==0)? Xq : (z==1)? Xk : Xv;
    g = blockIdx.x;                       // 0..127
    dst = D + (size_t)(g*64 + wave*16)*512 + lane*8;
  } else {
    const int wz = blockIdx.x>>5, gg = blockIdx.x&31;
    S = (wz==0)? Wq : (wz==1)? Wk : (wz==2)? Wv : Wo;
    g = gg;
    dst = Wp + (size_t)((wz*32 + gg)*64 + wave*16)*512 + lane*8;
  }
  const float* src = S + (size_t)(g*32 + l31)*DMODEL + 8*hi + 256*wave;
  #pragma unroll
  for (int i=0;i<16;i++)
    *(ushort8v*)(dst + (size_t)i*512) = cvt8(src + 16*i);
}

// ---------- A packer (bf16): Am[q32][kt][w][lane][8] = bf16(A[k][q]) ----------
__global__ __launch_bounds__(256) void cvtA(const float* __restrict__ A,
                                            unsigned short* __restrict__ Am){
  const int tid  = threadIdx.x;
  const int lane = tid&63, l31 = lane&31, hi = lane>>5;
  const int q32  = blockIdx.x;                 // 0..63
  const int kt   = blockIdx.y*4 + (tid>>6);    // 0..31
  const int q    = q32*32 + l31;

  unsigned short out8[4][8];
  #pragma unroll
  for (int fi=0; fi<2; fi++){
    #pragma unroll
    for (int mm=0; mm<4; mm++){
      #pragma unroll
      for (int j=0; j<4; j++){
        const int k = kt*64 + 32*fi + 8*mm + 4*hi + j;
        out8[fi*2 + (mm>>1)][(mm&1)*4 + j] = f2b(A[(size_t)k*SEQ + q]);
      }
    }
  }
  unsigned short* dst = Am + ((size_t)(q32*32 + kt)*4)*512 + lane*8;
  #pragma unroll
  for (int w=0; w<4; w++)
    *(ushort8v*)(dst + (size_t)w*512) = *(const ushort8v*)out8[w];
}

// ---------- fused q/k/v projection: fragment GEMM, 8-wave K-split ----------
// 512 thr = (wr 0..1) x (wc 0..1) x (ks 0..1); each wave half the K sweep;
// partials merged via conflict-free LDS overlay (oproj-proven pattern).
__global__ __launch_bounds__(512,2) void proj_qkv(
    const unsigned short* __restrict__ Xq, const unsigned short* __restrict__ Xk, const unsigned short* __restrict__ Xv,
    const unsigned short* __restrict__ Wp,
    const float* __restrict__ bq, const float* __restrict__ bk, const float* __restrict__ bv,
    unsigned short* __restrict__ qh, unsigned short* __restrict__ Kp, unsigned short* __restrict__ Vp)
{
  const int z = blockIdx.z;
  const unsigned short* X = (z==0)? Xq : (z==1)? Xk : Xv;
  const unsigned short* W = Wp + (size_t)z*1048576;
  const float* bias = (z==0)? bq : (z==1)? bk : bv;
  const float alpha = (z==0)? 0.125f : 1.0f;   // fold 1/sqrt(DK) into qh

  const int orig = blockIdx.y*8 + blockIdx.x;
  const int virt = (orig&7)*32 + (orig>>3);
  const int bx = virt&7, by = virt>>3;
  const int mb = by*128, nb = bx*128;

  const int tid = threadIdx.x;
  const int lane = tid&63, wave = tid>>6;          // 0..7
  const int wc = wave&1, wr = (wave>>1)&1, ks = wave>>2;
  const int l31 = lane&31, hi = lane>>5;
  f32x16 acc[2][2] = {};

  const unsigned short* a0p = X + (size_t)((mb>>5) + 2*wr)*32768 + lane*8;
  const unsigned short* a1p = a0p + 32768;
  const unsigned short* b0p = W + (size_t)((nb>>5) + 2*wc)*32768 + lane*8;
  const unsigned short* b1p = b0p + 32768;

  const int sbase = ks*32;
  #pragma unroll 8
  for (int s0=0; s0<32; s0++){
    const int s = sbase + s0;
    bf16x8 a0 = *(const bf16x8*)(a0p + (size_t)s*512);
    bf16x8 a1 = *(const bf16x8*)(a1p + (size_t)s*512);
    bf16x8 b0 = *(const bf16x8*)(b0p + (size_t)s*512);
    bf16x8 b1 = *(const bf16x8*)(b1p + (size_t)s*512);
    acc[0][0] = mfma32(a0,b0,acc[0][0]);
    acc[0][1] = mfma32(a0,b1,acc[0][1]);
    acc[1][0] = mfma32(a1,b0,acc[1][0]);
    acc[1][1] = mfma32(a1,b1,acc[1][1]);
  }

  // cross-ks reduction: ks=1 waves deposit, ks=0 waves add + store
  __shared__ float red[4][64][65];     // 66560 B, stride 65 -> conflict-free
  if (ks==1){
    #pragma unroll
    for (int fi=0; fi<2; fi++)
      #pragma unroll
      for (int fj=0; fj<2; fj++)
        #pragma unroll
        for (int r=0;r<16;r++)
          red[wr*2+wc][lane][(fi*2+fj)*16 + r] = acc[fi][fj][r];
  }
  __syncthreads();
  if (ks==0){
    #pragma unroll
    for (int fi=0; fi<2; fi++)
      #pragma unroll
      for (int fj=0; fj<2; fj++)
        #pragma unroll
        for (int r=0;r<16;r++)
          acc[fi][fj][r] += red[wr*2+wc][lane][(fi*2+fj)*16 + r];

    #pragma unroll
    for (int fj=0; fj<2; fj++){
      const int e = nb + 64*wc + 32*fj + l31;
      const float bv_ = bias[e];
      const int hh = e>>6, dk = e&63;
      #pragma unroll
      for (int fi=0; fi<2; fi++){
        #pragma unroll
        for (int r=0;r<16;r++){
          const int i = mb + 64*wr + 32*fi + (r&3) + 8*(r>>2) + 4*hi;
          const int bb = i>>11, ss = i&(SEQ-1);
          const int bhh = bb*NHEAD + hh;
          const unsigned short val = f2b((acc[fi][fj][r] + bv_)*alpha);
          if (z==0){
            qh[((size_t)bhh*SEQ + ss)*DHEAD + dk] = val;
          } else if (z==1){
            const size_t addr = (((size_t)(bhh*64 + (ss>>5))*4 + (dk>>4))*64
                                 + ((dk>>3)&1)*32 + (ss&31))*8 + (dk&7);
            Kp[addr] = val;
          } else {
            const size_t addr = ((((size_t)(bhh*32 + (ss>>6))*4 + ((ss>>4)&3))*2
                                 + (dk>>5))*64 + ((ss>>3)&1)*32 + (dk&31))*8 + (ss&7);
            Vp[addr] = val;
          }
        }
      }
    }
  }
}

// ---------- fused masked attention: x = (Qh Kh^T ∘ A^T) Vh ----------
// R12 structure + T4 counted vmcnt: raw s_barrier pairs, loads stay in flight
// across barriers (never drain to 0 in the main loop).
__global__ __launch_bounds__(512,4) void attn(
    const unsigned short* __restrict__ qh, const unsigned short* __restrict__ Kp,
    const unsigned short* __restrict__ Vp, const unsigned short* __restrict__ Am,
    unsigned short* __restrict__ xp)
{
  const int orig = blockIdx.y*16 + blockIdx.x;
  const int xcd = orig&7, within = orig>>3;   // within 0..63
  const int bh   = xcd*4 + (within>>4);       // 0..31
  const int qblk = within&15;                 // 0..15 (128 q-rows each)

  const int tid  = threadIdx.x;
  const int lane = tid&63, wave = tid>>6;     // wave 0..7
  const int qsub = wave&3, khalf = wave>>2;
  const int l31 = lane&31, hi = lane>>5;

  const int q32  = qblk*4 + qsub;
  const int qrow = q32*32 + l31;
  const unsigned short* qp = qh + ((size_t)bh*SEQ + qrow)*DHEAD;
  bf16x8 Qf[4];
  #pragma unroll
  for (int t=0;t<4;t++) Qf[t] = *(const bf16x8*)(qp + 16*t + 8*hi);

  f32x16 xacc[2] = {};

  const unsigned short* kpb = Kp + (size_t)bh*131072 + lane*8;   // [kt][frag][lane][8]
  const unsigned short* vpb = Vp + (size_t)bh*131072 + lane*8;
  const unsigned short* apb = Am + (size_t)q32*65536 + lane*8;   // [kt][w][lane][8]

  // staging: [buf][16 frags (K 0..7 | V 8..15)][512 shorts] = 32 KB;
  // reused post-loop as float Red[4][64][33] = 33792 B
  __shared__ float SMEMf[8448];
  unsigned short* smem = (unsigned short*)SMEMf;

  const unsigned short* gsb = ((wave<4)? kpb : vpb);
  const int fo = (wave&3)*2;                       // fragment pair within K or V
  const int dof = ((wave<4)? 0 : 4096) + fo*512;   // LDS dest offset (shorts)

  ushort8v Aa[2], Ab[2];

  // per tile per wave: 4 gload_lds + 2 A reg-loads = 6 vmem ops
  #define STAGE(BUF, KT) { \
    const unsigned short* _g = gsb + (size_t)(KT)*4096 + (size_t)fo*512; \
    GLOAD16(_g,       smem + (BUF)*8192 + dof); \
    GLOAD16(_g + 512, smem + (BUF)*8192 + dof + 512); }

  #define LOADA(DST, KT) { \
    const unsigned short* _ap = apb + (size_t)(KT)*2048 + (size_t)(khalf*2)*512; \
    DST[0] = *(const ushort8v*)(_ap); \
    DST[1] = *(const ushort8v*)(_ap + 512); }

  // prologue: tiles 0 and 1 in flight (12 vmem ops)
  STAGE(0, 0);  LOADA(Aa, 0);
  STAGE(1, 1);  LOADA(Ab, 1);

  // ITER: wait own tile-T ops (counted, NOT 0) -> barrier -> compute ->
  //       barrier -> stage tile T+2 (if DOSTAGE). Loads for T+1 stay in flight.
  #define ITER(T, BUF, AR, VM, DOSTAGE) { \
    asm volatile("s_waitcnt vmcnt(" VM ")" ::: "memory"); \
    __builtin_amdgcn_sched_barrier(0); \
    __builtin_amdgcn_s_barrier(); \
    __builtin_amdgcn_sched_barrier(0); \
    unsigned int wv[4], xv[4]; \
    { \
      f32x16 sacc = {}; \
      _Pragma("unroll") \
      for (int s=0;s<4;s++){ \
        bf16x8 kf = *(const bf16x8*)(smem + (BUF)*8192 + (khalf*4+s)*512 + lane*8); \
        sacc = mfma32(kf, Qf[s], sacc); \
      } \
      ushort8v a80 = AR[0], a81 = AR[1]; \
      _Pragma("unroll") \
      for (int mm=0; mm<4; mm++){ \
        const int b0 = (mm&1)*4, rb2 = 4*mm; \
        float p0 = sacc[rb2+0]*((mm>>1)? b2f(a81[b0+0]) : b2f(a80[b0+0])); \
        float p1 = sacc[rb2+1]*((mm>>1)? b2f(a81[b0+1]) : b2f(a80[b0+1])); \
        float p2 = sacc[rb2+2]*((mm>>1)? b2f(a81[b0+2]) : b2f(a80[b0+2])); \
        float p3 = sacc[rb2+3]*((mm>>1)? b2f(a81[b0+3]) : b2f(a80[b0+3])); \
        asm("v_cvt_pk_bf16_f32 %0, %1, %2" : "=v"(wv[mm]) : "v"(p0), "v"(p1)); \
        asm("v_cvt_pk_bf16_f32 %0, %1, %2" : "=v"(xv[mm]) : "v"(p2), "v"(p3)); \
      } \
    } \
    __builtin_amdgcn_s_setprio(1); \
    _Pragma("unroll") \
    for (int sl=0; sl<2; sl++){ \
      const int s2 = 2*khalf + sl; \
      uint2v rw = __builtin_amdgcn_permlane32_swap(wv[2*sl], wv[2*sl+1], false, false); \
      uint2v rx = __builtin_amdgcn_permlane32_swap(xv[2*sl], xv[2*sl+1], false, false); \
      int4v av; av.x = (int)rw[0]; av.y = (int)rx[0]; av.z = (int)rw[1]; av.w = (int)rx[1]; \
      bf16x8 pa = __builtin_bit_cast(bf16x8, av); \
      bf16x8 v0 = *(const bf16x8*)(smem + (BUF)*8192 + 4096 + (s2*2+0)*512 + lane*8); \
      bf16x8 v1 = *(const bf16x8*)(smem + (BUF)*8192 + 4096 + (s2*2+1)*512 + lane*8); \
      xacc[0] = mfma32(pa, v0, xacc[0]); \
      xacc[1] = mfma32(pa, v1, xacc[1]); \
    } \
    __builtin_amdgcn_s_setprio(0); \
    __builtin_amdgcn_sched_barrier(0); \
    __builtin_amdgcn_s_barrier(); \
    __builtin_amdgcn_sched_barrier(0); \
    if (DOSTAGE){ \
      STAGE(BUF, (T)+2); \
      LOADA(AR, (T)+2); \
    } }

  // t = 0..29: full pipeline (stages t+2 = 2..31, no wraparound)
  #pragma unroll 1
  for (int tt=0; tt<15; tt++){
    const int t0 = 2*tt, t1 = 2*tt+1;
    ITER(t0, 0, Aa, "6", 1);
    ITER(t1, 1, Ab, "6", 1);
  }
  // tail: t=30 (nothing more to stage), t=31 (drain)
  ITER(30, 0, Aa, "6", 0);
  ITER(31, 1, Ab, "0", 0);
  #undef ITER
  #undef STAGE
  #undef LOADA

  // cross-khalf reduction through the (now dead) staging LDS
  float* red = SMEMf;   // [4][64][33]
  __syncthreads();
  if (khalf==1){
    #pragma unroll
    for (int j=0;j<2;j++)
      #pragma unroll
      for (int r=0;r<16;r++)
        red[((qsub*64 + lane)*33) + 16*j + r] = xacc[j][r];
  }
  __syncthreads();
  if (khalf==0){
    #pragma unroll
    for (int j=0;j<2;j++)
      #pragma unroll
      for (int r=0;r<16;r++)
        xacc[j][r] += red[((qsub*64 + lane)*33) + 16*j + r];
    const int b = bh>>4, h = bh&15;
    #pragma unroll
    for (int fj=0; fj<2; fj++){
      const int scol = h*4 + fj*2 + (l31>>4);
      const int lpart = ((l31>>3)&1)*32;
      const int epart = l31&7;
      #pragma unroll
      for (int r=0;r<16;r++){
        const int qq = q32*32 + (r&3) + 8*(r>>2) + 4*hi;
        const int row = b*SEQ + qq;
        const size_t addr = ((size_t)(row>>5)*64 + scol)*512 + (lpart + (row&31))*8 + epart;
        xp[addr] = f2b(xacc[fj][r]);
      }
    }
  }
}

// ---------- output projection: 128x128 fragment GEMM, 8-wave K-split, fp32 out ----------
__global__ __launch_bounds__(512,2) void oproj(
    const unsigned short* __restrict__ Xp, const unsigned short* __restrict__ Wop,
    const float* __restrict__ bo, float* __restrict__ out)
{
  const int orig = blockIdx.y*8 + blockIdx.x;
  const int virt = (orig&7)*32 + (orig>>3);
  const int bx = virt&7, by = virt>>3;
  const int mb = by*128, nb = bx*128;

  const int tid = threadIdx.x;
  const int lane = tid&63, wave = tid>>6;          // 0..7
  const int wc = wave&1, wr = (wave>>1)&1, ks = wave>>2;
  const int l31 = lane&31, hi = lane>>5;
  f32x16 acc[2][2] = {};

  const unsigned short* a0p = Xp  + (size_t)((mb>>5) + 2*wr)*32768 + lane*8;
  const unsigned short* a1p = a0p + 32768;
  const unsigned short* b0p = Wop + (size_t)((nb>>5) + 2*wc)*32768 + lane*8;
  const unsigned short* b1p = b0p + 32768;

  const int sbase = ks*32;
  #pragma unroll 8
  for (int s0=0; s0<32; s0++){
    const int s = sbase + s0;
    bf16x8 a0 = *(const bf16x8*)(a0p + (size_t)s*512);
    bf16x8 a1 = *(const bf16x8*)(a1p + (size_t)s*512);
    bf16x8 b0 = *(const bf16x8*)(b0p + (size_t)s*512);
    bf16x8 b1 = *(const bf16x8*)(b1p + (size_t)s*512);
    acc[0][0] = mfma32(a0,b0,acc[0][0]);
    acc[0][1] = mfma32(a0,b1,acc[0][1]);
    acc[1][0] = mfma32(a1,b0,acc[1][0]);
    acc[1][1] = mfma32(a1,b1,acc[1][1]);
  }

  // cross-ks reduction: ks=1 waves deposit, ks=0 waves add + store
  __shared__ float red[4][64][65];     // 66560 B, stride 65 -> conflict-free
  if (ks==1){
    #pragma unroll
    for (int fi=0; fi<2; fi++)
      #pragma unroll
      for (int fj=0; fj<2; fj++)
        #pragma unroll
        for (int r=0;r<16;r++)
          red[wr*2+wc][lane][(fi*2+fj)*16 + r] = acc[fi][fj][r];
  }
  __syncthreads();
  if (ks==0){
    #pragma unroll
    for (int fi=0; fi<2; fi++)
      #pragma unroll
      for (int fj=0; fj<2; fj++)
        #pragma unroll
        for (int r=0;r<16;r++)
          acc[fi][fj][r] += red[wr*2+wc][lane][(fi*2+fj)*16 + r];
    #pragma unroll
    for (int fj=0; fj<2; fj++){
      const int e = nb + 64*wc + 32*fj + l31;
      const float bv_ = bo[e];
      #pragma unroll
      for (int fi=0; fi<2; fi++){
        #pragma unroll
        for (int r=0;r<16;r++){
          const int i = mb + 64*wr + 32*fi + (r&3) + 8*(r>>2) + 4*hi;
          out[(size_t)i*DMODEL + e] = acc[fi][fj][r] + bv_;
        }
      }
    }
  }
}

extern "C" void kernel_launch(void* const* d_in, const int* in_sizes, int n_in,
                              void* d_out, int out_size, void* d_ws, size_t ws_size,
                              hipStream_t stream)
{
  const float* q  = (const float*)d_in[0];
  const float* k  = (const float*)d_in[1];
  const float* v  = (const float*)d_in[2];
  const float* A  = (const float*)d_in[3];
  const float* Wq = (const float*)d_in[4];
  const float* bq = (const float*)d_in[5];
  const float* Wk = (const float*)d_in[6];
  const float* bk = (const float*)d_in[7];
  const float* Wv = (const float*)d_in[8];
  const float* bv = (const float*)d_in[9];
  const float* Wo = (const float*)d_in[10];
  const float* bo = (const float*)d_in[11];
  float* out = (float*)d_out;

  // ws (bf16 elems): qh, Kp, Vp, xb, Wp -> 40MB. d_out as scratch:
  //   phase1: Xqp [0,8MB), Xkp [8,16MB)   (consumed by proj)
  //   phase2: Am bf16 [0,8MB)             (written by cvtA after proj, read by attn)
  //   phase3: final fp32 out              (oproj)
  unsigned short* ws = (unsigned short*)d_ws;
  const size_t NE = (size_t)NBATCH*SEQ*DMODEL;   // 4M elements
  unsigned short* qh  = ws;
  unsigned short* Kp  = qh + NE;
  unsigned short* Vp  = Kp + NE;
  unsigned short* xb  = Vp + NE;                 // Xvp before attn, packed-x after
  unsigned short* Wp  = xb + NE;                 // 4 packed weight matrices
  unsigned short* Xqp = (unsigned short*)d_out;
  unsigned short* Xkp = Xqp + NE;
  unsigned short* Am  = (unsigned short*)d_out;  // bf16 2048x2048 = 8MB
  unsigned short* Xvp = xb;

  cvtXW<<<dim3(128, 1, 4), 256, 0, stream>>>(q, k, v, Wq, Wk, Wv, Wo,
                                             Xqp, Xkp, Xvp, Wp);
  proj_qkv<<<dim3(8, 32, 3), 512, 0, stream>>>(
      Xqp, Xkp, Xvp, Wp, bq, bk, bv, qh, Kp, Vp);
  cvtA<<<dim3(64, 8), 256, 0, stream>>>(A, Am);
  attn<<<dim3(16, 32), 512, 0, stream>>>(qh, Kp, Vp, Am, xb);
  oproj<<<dim3(8, 32), 512, 0, stream>>>(xb, Wp + (size_t)3*1048576, bo, out);
}

// Round 18
// 125.954 us; speedup vs baseline: 1.1294x; 1.1294x over previous
//
#include <hip/hip_runtime.h>

#define SEQ    2048
#define DMODEL 1024
#define NHEAD  16
#define DHEAD  64
#define NBATCH 2

typedef __bf16 bf16x8 __attribute__((ext_vector_type(8)));
typedef float f32x16 __attribute__((ext_vector_type(16)));
typedef float f32x8 __attribute__((ext_vector_type(8)));
typedef unsigned short ushort8v __attribute__((ext_vector_type(8)));
typedef unsigned int uint2v __attribute__((ext_vector_type(2)));
typedef int int4v __attribute__((ext_vector_type(4)));

static __device__ __forceinline__ unsigned short f2b(float f){
  unsigned int u = __builtin_bit_cast(unsigned int, f);
  u += 0x7fffu + ((u>>16)&1u);            // RNE to bf16
  return (unsigned short)(u>>16);
}
static __device__ __forceinline__ float b2f(unsigned short h){
  unsigned int u = ((unsigned int)h)<<16;
  return __builtin_bit_cast(float, u);
}
static __device__ __forceinline__ f32x16 mfma32(bf16x8 a, bf16x8 b, f32x16 c){
  return __builtin_amdgcn_mfma_f32_32x32x16_bf16(a,b,c,0,0,0);
}
static __device__ __forceinline__ ushort8v cvt8(const float* p){
  float4 f0 = *(const float4*)p;
  float4 f1 = *(const float4*)(p+4);
  ushort8v r;
  r[0]=f2b(f0.x); r[1]=f2b(f0.y); r[2]=f2b(f0.z); r[3]=f2b(f0.w);
  r[4]=f2b(f1.x); r[5]=f2b(f1.y); r[6]=f2b(f1.z); r[7]=f2b(f1.w);
  return r;
}
#define GLOAD16(g,l) __builtin_amdgcn_global_load_lds( \
    (const __attribute__((address_space(1))) void*)(g), \
    (__attribute__((address_space(3))) void*)(l), 16, 0, 0)

// ---------- pack X (q,k,v) and W (q,k,v,o) fp32 -> bf16 MFMA fragment order ----------
__global__ __launch_bounds__(256) void cvtXW(
    const float* __restrict__ q, const float* __restrict__ k, const float* __restrict__ v,
    const float* __restrict__ Wq, const float* __restrict__ Wk,
    const float* __restrict__ Wv, const float* __restrict__ Wo,
    unsigned short* __restrict__ Xq, unsigned short* __restrict__ Xk, unsigned short* __restrict__ Xv,
    unsigned short* __restrict__ Wp)
{
  const int z = blockIdx.z;
  const int wave = threadIdx.x>>6, lane = threadIdx.x&63;
  const int l31 = lane&31, hi = lane>>5;
  const float* S;
  unsigned short* dst;
  int g;
  if (z < 3){
    S = (z==0)? q : (z==1)? k : v;
    unsigned short* D = (z==0)? Xq : (z==1)? Xk : Xv;
    g = blockIdx.x;                       // 0..127
    dst = D + (size_t)(g*64 + wave*16)*512 + lane*8;
  } else {
    const int wz = blockIdx.x>>5, gg = blockIdx.x&31;
    S = (wz==0)? Wq : (wz==1)? Wk : (wz==2)? Wv : Wo;
    g = gg;
    dst = Wp + (size_t)((wz*32 + gg)*64 + wave*16)*512 + lane*8;
  }
  const float* src = S + (size_t)(g*32 + l31)*DMODEL + 8*hi + 256*wave;
  #pragma unroll
  for (int i=0;i<16;i++)
    *(ushort8v*)(dst + (size_t)i*512) = cvt8(src + 16*i);
}

// ---------- A packer (bf16): Am[q32][kt][w][lane][8] = bf16(A[k][q]) ----------
__global__ __launch_bounds__(256) void cvtA(const float* __restrict__ A,
                                            unsigned short* __restrict__ Am){
  const int tid  = threadIdx.x;
  const int lane = tid&63, l31 = lane&31, hi = lane>>5;
  const int q32  = blockIdx.x;                 // 0..63
  const int kt   = blockIdx.y*4 + (tid>>6);    // 0..31
  const int q    = q32*32 + l31;

  unsigned short out8[4][8];
  #pragma unroll
  for (int fi=0; fi<2; fi++){
    #pragma unroll
    for (int mm=0; mm<4; mm++){
      #pragma unroll
      for (int j=0; j<4; j++){
        const int k = kt*64 + 32*fi + 8*mm + 4*hi + j;
        out8[fi*2 + (mm>>1)][(mm&1)*4 + j] = f2b(A[(size_t)k*SEQ + q]);
      }
    }
  }
  unsigned short* dst = Am + ((size_t)(q32*32 + kt)*4)*512 + lane*8;
  #pragma unroll
  for (int w=0; w<4; w++)
    *(ushort8v*)(dst + (size_t)w*512) = *(const ushort8v*)out8[w];
}

// ---------- fused q/k/v projection: LDS-free, barrier-free fragment GEMM ----------
// (R16 version: 256 thr, 3 blocks/CU grid-resident in one round — K-split
//  regressed here because 66.5KB LDS would cap residency at 2/CU; the
//  K-split recipe requires grid <= 256 blocks. Keep this form.)
__global__ __launch_bounds__(256,3) void proj_qkv(
    const unsigned short* __restrict__ Xq, const unsigned short* __restrict__ Xk, const unsigned short* __restrict__ Xv,
    const unsigned short* __restrict__ Wp,
    const float* __restrict__ bq, const float* __restrict__ bk, const float* __restrict__ bv,
    unsigned short* __restrict__ qh, unsigned short* __restrict__ Kp, unsigned short* __restrict__ Vp)
{
  const int z = blockIdx.z;
  const unsigned short* X = (z==0)? Xq : (z==1)? Xk : Xv;
  const unsigned short* W = Wp + (size_t)z*1048576;
  const float* bias = (z==0)? bq : (z==1)? bk : bv;
  const float alpha = (z==0)? 0.125f : 1.0f;   // fold 1/sqrt(DK) into qh

  const int orig = blockIdx.y*8 + blockIdx.x;
  const int virt = (orig&7)*32 + (orig>>3);
  const int bx = virt&7, by = virt>>3;
  const int mb = by*128, nb = bx*128;

  const int tid = threadIdx.x;
  const int lane = tid&63, wave = tid>>6;
  const int wr = wave>>1, wc = wave&1, l31 = lane&31, hi = lane>>5;
  f32x16 acc[2][2] = {};

  const unsigned short* a0p = X + (size_t)((mb>>5) + 2*wr)*32768 + lane*8;
  const unsigned short* a1p = a0p + 32768;
  const unsigned short* b0p = W + (size_t)((nb>>5) + 2*wc)*32768 + lane*8;
  const unsigned short* b1p = b0p + 32768;

  #pragma unroll 8
  for (int s=0;s<64;s++){
    bf16x8 a0 = *(const bf16x8*)(a0p + (size_t)s*512);
    bf16x8 a1 = *(const bf16x8*)(a1p + (size_t)s*512);
    bf16x8 b0 = *(const bf16x8*)(b0p + (size_t)s*512);
    bf16x8 b1 = *(const bf16x8*)(b1p + (size_t)s*512);
    acc[0][0] = mfma32(a0,b0,acc[0][0]);
    acc[0][1] = mfma32(a0,b1,acc[0][1]);
    acc[1][0] = mfma32(a1,b0,acc[1][0]);
    acc[1][1] = mfma32(a1,b1,acc[1][1]);
  }

  #pragma unroll
  for (int fj=0; fj<2; fj++){
    const int e = nb + 64*wc + 32*fj + l31;
    const float bv_ = bias[e];
    const int hh = e>>6, dk = e&63;
    #pragma unroll
    for (int fi=0; fi<2; fi++){
      #pragma unroll
      for (int r=0;r<16;r++){
        const int i = mb + 64*wr + 32*fi + (r&3) + 8*(r>>2) + 4*hi;
        const int bb = i>>11, ss = i&(SEQ-1);
        const int bhh = bb*NHEAD + hh;
        const unsigned short val = f2b((acc[fi][fj][r] + bv_)*alpha);
        if (z==0){
          qh[((size_t)bhh*SEQ + ss)*DHEAD + dk] = val;
        } else if (z==1){
          const size_t addr = (((size_t)(bhh*64 + (ss>>5))*4 + (dk>>4))*64
                               + ((dk>>3)&1)*32 + (ss&31))*8 + (dk&7);
          Kp[addr] = val;
        } else {
          const size_t addr = ((((size_t)(bhh*32 + (ss>>6))*4 + ((ss>>4)&3))*2
                               + (dk>>5))*64 + ((ss>>3)&1)*32 + (dk&31))*8 + (ss&7);
          Vp[addr] = val;
        }
      }
    }
  }
}

// ---------- fused masked attention: x = (Qh Kh^T ∘ A^T) Vh ----------
// R12 structure + T4 counted vmcnt: raw s_barrier pairs, loads stay in flight
// across barriers (never drain to 0 in the main loop).
__global__ __launch_bounds__(512,4) void attn(
    const unsigned short* __restrict__ qh, const unsigned short* __restrict__ Kp,
    const unsigned short* __restrict__ Vp, const unsigned short* __restrict__ Am,
    unsigned short* __restrict__ xp)
{
  const int orig = blockIdx.y*16 + blockIdx.x;
  const int xcd = orig&7, within = orig>>3;   // within 0..63
  const int bh   = xcd*4 + (within>>4);       // 0..31
  const int qblk = within&15;                 // 0..15 (128 q-rows each)

  const int tid  = threadIdx.x;
  const int lane = tid&63, wave = tid>>6;     // wave 0..7
  const int qsub = wave&3, khalf = wave>>2;
  const int l31 = lane&31, hi = lane>>5;

  const int q32  = qblk*4 + qsub;
  const int qrow = q32*32 + l31;
  const unsigned short* qp = qh + ((size_t)bh*SEQ + qrow)*DHEAD;
  bf16x8 Qf[4];
  #pragma unroll
  for (int t=0;t<4;t++) Qf[t] = *(const bf16x8*)(qp + 16*t + 8*hi);

  f32x16 xacc[2] = {};

  const unsigned short* kpb = Kp + (size_t)bh*131072 + lane*8;   // [kt][frag][lane][8]
  const unsigned short* vpb = Vp + (size_t)bh*131072 + lane*8;
  const unsigned short* apb = Am + (size_t)q32*65536 + lane*8;   // [kt][w][lane][8]

  // staging: [buf][16 frags (K 0..7 | V 8..15)][512 shorts] = 32 KB;
  // reused post-loop as float Red[4][64][33] = 33792 B
  __shared__ float SMEMf[8448];
  unsigned short* smem = (unsigned short*)SMEMf;

  const unsigned short* gsb = ((wave<4)? kpb : vpb);
  const int fo = (wave&3)*2;                       // fragment pair within K or V
  const int dof = ((wave<4)? 0 : 4096) + fo*512;   // LDS dest offset (shorts)

  ushort8v Aa[2], Ab[2];

  // per tile per wave: 4 gload_lds + 2 A reg-loads = 6 vmem ops
  #define STAGE(BUF, KT) { \
    const unsigned short* _g = gsb + (size_t)(KT)*4096 + (size_t)fo*512; \
    GLOAD16(_g,       smem + (BUF)*8192 + dof); \
    GLOAD16(_g + 512, smem + (BUF)*8192 + dof + 512); }

  #define LOADA(DST, KT) { \
    const unsigned short* _ap = apb + (size_t)(KT)*2048 + (size_t)(khalf*2)*512; \
    DST[0] = *(const ushort8v*)(_ap); \
    DST[1] = *(const ushort8v*)(_ap + 512); }

  // prologue: tiles 0 and 1 in flight (12 vmem ops)
  STAGE(0, 0);  LOADA(Aa, 0);
  STAGE(1, 1);  LOADA(Ab, 1);

  // ITER: wait own tile-T ops (counted, NOT 0) -> barrier -> compute ->
  //       barrier -> stage tile T+2 (if DOSTAGE). Loads for T+1 stay in flight.
  #define ITER(T, BUF, AR, VM, DOSTAGE) { \
    asm volatile("s_waitcnt vmcnt(" VM ")" ::: "memory"); \
    __builtin_amdgcn_sched_barrier(0); \
    __builtin_amdgcn_s_barrier(); \
    __builtin_amdgcn_sched_barrier(0); \
    unsigned int wv[4], xv[4]; \
    { \
      f32x16 sacc = {}; \
      _Pragma("unroll") \
      for (int s=0;s<4;s++){ \
        bf16x8 kf = *(const bf16x8*)(smem + (BUF)*8192 + (khalf*4+s)*512 + lane*8); \
        sacc = mfma32(kf, Qf[s], sacc); \
      } \
      ushort8v a80 = AR[0], a81 = AR[1]; \
      _Pragma("unroll") \
      for (int mm=0; mm<4; mm++){ \
        const int b0 = (mm&1)*4, rb2 = 4*mm; \
        float p0 = sacc[rb2+0]*((mm>>1)? b2f(a81[b0+0]) : b2f(a80[b0+0])); \
        float p1 = sacc[rb2+1]*((mm>>1)? b2f(a81[b0+1]) : b2f(a80[b0+1])); \
        float p2 = sacc[rb2+2]*((mm>>1)? b2f(a81[b0+2]) : b2f(a80[b0+2])); \
        float p3 = sacc[rb2+3]*((mm>>1)? b2f(a81[b0+3]) : b2f(a80[b0+3])); \
        asm("v_cvt_pk_bf16_f32 %0, %1, %2" : "=v"(wv[mm]) : "v"(p0), "v"(p1)); \
        asm("v_cvt_pk_bf16_f32 %0, %1, %2" : "=v"(xv[mm]) : "v"(p2), "v"(p3)); \
      } \
    } \
    __builtin_amdgcn_s_setprio(1); \
    _Pragma("unroll") \
    for (int sl=0; sl<2; sl++){ \
      const int s2 = 2*khalf + sl; \
      uint2v rw = __builtin_amdgcn_permlane32_swap(wv[2*sl], wv[2*sl+1], false, false); \
      uint2v rx = __builtin_amdgcn_permlane32_swap(xv[2*sl], xv[2*sl+1], false, false); \
      int4v av; av.x = (int)rw[0]; av.y = (int)rx[0]; av.z = (int)rw[1]; av.w = (int)rx[1]; \
      bf16x8 pa = __builtin_bit_cast(bf16x8, av); \
      bf16x8 v0 = *(const bf16x8*)(smem + (BUF)*8192 + 4096 + (s2*2+0)*512 + lane*8); \
      bf16x8 v1 = *(const bf16x8*)(smem + (BUF)*8192 + 4096 + (s2*2+1)*512 + lane*8); \
      xacc[0] = mfma32(pa, v0, xacc[0]); \
      xacc[1] = mfma32(pa, v1, xacc[1]); \
    } \
    __builtin_amdgcn_s_setprio(0); \
    __builtin_amdgcn_sched_barrier(0); \
    __builtin_amdgcn_s_barrier(); \
    __builtin_amdgcn_sched_barrier(0); \
    if (DOSTAGE){ \
      STAGE(BUF, (T)+2); \
      LOADA(AR, (T)+2); \
    } }

  // t = 0..29: full pipeline (stages t+2 = 2..31, no wraparound)
  #pragma unroll 1
  for (int tt=0; tt<15; tt++){
    const int t0 = 2*tt, t1 = 2*tt+1;
    ITER(t0, 0, Aa, "6", 1);
    ITER(t1, 1, Ab, "6", 1);
  }
  // tail: t=30 (nothing more to stage), t=31 (drain)
  ITER(30, 0, Aa, "6", 0);
  ITER(31, 1, Ab, "0", 0);
  #undef ITER
  #undef STAGE
  #undef LOADA

  // cross-khalf reduction through the (now dead) staging LDS
  float* red = SMEMf;   // [4][64][33]
  __syncthreads();
  if (khalf==1){
    #pragma unroll
    for (int j=0;j<2;j++)
      #pragma unroll
      for (int r=0;r<16;r++)
        red[((qsub*64 + lane)*33) + 16*j + r] = xacc[j][r];
  }
  __syncthreads();
  if (khalf==0){
    #pragma unroll
    for (int j=0;j<2;j++)
      #pragma unroll
      for (int r=0;r<16;r++)
        xacc[j][r] += red[((qsub*64 + lane)*33) + 16*j + r];
    const int b = bh>>4, h = bh&15;
    #pragma unroll
    for (int fj=0; fj<2; fj++){
      const int scol = h*4 + fj*2 + (l31>>4);
      const int lpart = ((l31>>3)&1)*32;
      const int epart = l31&7;
      #pragma unroll
      for (int r=0;r<16;r++){
        const int qq = q32*32 + (r&3) + 8*(r>>2) + 4*hi;
        const int row = b*SEQ + qq;
        const size_t addr = ((size_t)(row>>5)*64 + scol)*512 + (lpart + (row&31))*8 + epart;
        xp[addr] = f2b(xacc[fj][r]);
      }
    }
  }
}

// ---------- output projection: 128x128 fragment GEMM, 8-wave K-split, fp32 out ----------
// (K-split valid here: grid = 256 blocks = 1/CU, LDS doesn't cut residency.)
__global__ __launch_bounds__(512,2) void oproj(
    const unsigned short* __restrict__ Xp, const unsigned short* __restrict__ Wop,
    const float* __restrict__ bo, float* __restrict__ out)
{
  const int orig = blockIdx.y*8 + blockIdx.x;
  const int virt = (orig&7)*32 + (orig>>3);
  const int bx = virt&7, by = virt>>3;
  const int mb = by*128, nb = bx*128;

  const int tid = threadIdx.x;
  const int lane = tid&63, wave = tid>>6;          // 0..7
  const int wc = wave&1, wr = (wave>>1)&1, ks = wave>>2;
  const int l31 = lane&31, hi = lane>>5;
  f32x16 acc[2][2] = {};

  const unsigned short* a0p = Xp  + (size_t)((mb>>5) + 2*wr)*32768 + lane*8;
  const unsigned short* a1p = a0p + 32768;
  const unsigned short* b0p = Wop + (size_t)((nb>>5) + 2*wc)*32768 + lane*8;
  const unsigned short* b1p = b0p + 32768;

  const int sbase = ks*32;
  #pragma unroll 8
  for (int s0=0; s0<32; s0++){
    const int s = sbase + s0;
    bf16x8 a0 = *(const bf16x8*)(a0p + (size_t)s*512);
    bf16x8 a1 = *(const bf16x8*)(a1p + (size_t)s*512);
    bf16x8 b0 = *(const bf16x8*)(b0p + (size_t)s*512);
    bf16x8 b1 = *(const bf16x8*)(b1p + (size_t)s*512);
    acc[0][0] = mfma32(a0,b0,acc[0][0]);
    acc[0][1] = mfma32(a0,b1,acc[0][1]);
    acc[1][0] = mfma32(a1,b0,acc[1][0]);
    acc[1][1] = mfma32(a1,b1,acc[1][1]);
  }

  // cross-ks reduction: ks=1 waves deposit, ks=0 waves add + store
  __shared__ float red[4][64][65];     // 66560 B, stride 65 -> conflict-free
  if (ks==1){
    #pragma unroll
    for (int fi=0; fi<2; fi++)
      #pragma unroll
      for (int fj=0; fj<2; fj++)
        #pragma unroll
        for (int r=0;r<16;r++)
          red[wr*2+wc][lane][(fi*2+fj)*16 + r] = acc[fi][fj][r];
  }
  __syncthreads();
  if (ks==0){
    #pragma unroll
    for (int fi=0; fi<2; fi++)
      #pragma unroll
      for (int fj=0; fj<2; fj++)
        #pragma unroll
        for (int r=0;r<16;r++)
          acc[fi][fj][r] += red[wr*2+wc][lane][(fi*2+fj)*16 + r];
    #pragma unroll
    for (int fj=0; fj<2; fj++){
      const int e = nb + 64*wc + 32*fj + l31;
      const float bv_ = bo[e];
      #pragma unroll
      for (int fi=0; fi<2; fi++){
        #pragma unroll
        for (int r=0;r<16;r++){
          const int i = mb + 64*wr + 32*fi + (r&3) + 8*(r>>2) + 4*hi;
          out[(size_t)i*DMODEL + e] = acc[fi][fj][r] + bv_;
        }
      }
    }
  }
}

extern "C" void kernel_launch(void* const* d_in, const int* in_sizes, int n_in,
                              void* d_out, int out_size, void* d_ws, size_t ws_size,
                              hipStream_t stream)
{
  const float* q  = (const float*)d_in[0];
  const float* k  = (const float*)d_in[1];
  const float* v  = (const float*)d_in[2];
  const float* A  = (const float*)d_in[3];
  const float* Wq = (const float*)d_in[4];
  const float* bq = (const float*)d_in[5];
  const float* Wk = (const float*)d_in[6];
  const float* bk = (const float*)d_in[7];
  const float* Wv = (const float*)d_in[8];
  const float* bv = (const float*)d_in[9];
  const float* Wo = (const float*)d_in[10];
  const float* bo = (const float*)d_in[11];
  float* out = (float*)d_out;

  // ws (bf16 elems): qh, Kp, Vp, xb, Wp -> 40MB. d_out as scratch:
  //   phase1: Xqp [0,8MB), Xkp [8,16MB)   (consumed by proj)
  //   phase2: Am bf16 [0,8MB)             (written by cvtA after proj, read by attn)
  //   phase3: final fp32 out              (oproj)
  unsigned short* ws = (unsigned short*)d_ws;
  const size_t NE = (size_t)NBATCH*SEQ*DMODEL;   // 4M elements
  unsigned short* qh  = ws;
  unsigned short* Kp  = qh + NE;
  unsigned short* Vp  = Kp + NE;
  unsigned short* xb  = Vp + NE;                 // Xvp before attn, packed-x after
  unsigned short* Wp  = xb + NE;                 // 4 packed weight matrices
  unsigned short* Xqp = (unsigned short*)d_out;
  unsigned short* Xkp = Xqp + NE;
  unsigned short* Am  = (unsigned short*)d_out;  // bf16 2048x2048 = 8MB
  unsigned short* Xvp = xb;

  cvtXW<<<dim3(128, 1, 4), 256, 0, stream>>>(q, k, v, Wq, Wk, Wv, Wo,
                                             Xqp, Xkp, Xvp, Wp);
  proj_qkv<<<dim3(8, 32, 3), 256, 0, stream>>>(
      Xqp, Xkp, Xvp, Wp, bq, bk, bv, qh, Kp, Vp);
  cvtA<<<dim3(64, 8), 256, 0, stream>>>(A, Am);
  attn<<<dim3(16, 32), 512, 0, stream>>>(qh, Kp, Vp, Am, xb);
  oproj<<<dim3(8, 32), 512, 0, stream>>>(xb, Wp + (size_t)3*1048576, bo, out);
}

// Round 19
// 122.012 us; speedup vs baseline: 1.1659x; 1.0323x over previous
//
#include <hip/hip_runtime.h>

#define SEQ    2048
#define DMODEL 1024
#define NHEAD  16
#define DHEAD  64
#define NBATCH 2

typedef __bf16 bf16x8 __attribute__((ext_vector_type(8)));
typedef float f32x16 __attribute__((ext_vector_type(16)));
typedef float f32x8 __attribute__((ext_vector_type(8)));
typedef unsigned short ushort8v __attribute__((ext_vector_type(8)));
typedef unsigned int uint2v __attribute__((ext_vector_type(2)));
typedef int int4v __attribute__((ext_vector_type(4)));

static __device__ __forceinline__ unsigned short f2b(float f){
  unsigned int u = __builtin_bit_cast(unsigned int, f);
  u += 0x7fffu + ((u>>16)&1u);            // RNE to bf16
  return (unsigned short)(u>>16);
}
static __device__ __forceinline__ float b2f(unsigned short h){
  unsigned int u = ((unsigned int)h)<<16;
  return __builtin_bit_cast(float, u);
}
static __device__ __forceinline__ f32x16 mfma32(bf16x8 a, bf16x8 b, f32x16 c){
  return __builtin_amdgcn_mfma_f32_32x32x16_bf16(a,b,c,0,0,0);
}
static __device__ __forceinline__ ushort8v cvt8(const float* p){
  float4 f0 = *(const float4*)p;
  float4 f1 = *(const float4*)(p+4);
  ushort8v r;
  r[0]=f2b(f0.x); r[1]=f2b(f0.y); r[2]=f2b(f0.z); r[3]=f2b(f0.w);
  r[4]=f2b(f1.x); r[5]=f2b(f1.y); r[6]=f2b(f1.z); r[7]=f2b(f1.w);
  return r;
}
#define GLOAD16(g,l) __builtin_amdgcn_global_load_lds( \
    (const __attribute__((address_space(1))) void*)(g), \
    (__attribute__((address_space(3))) void*)(l), 16, 0, 0)

// ---------- pack X (q,k,v) and W (q,k,v,o) fp32 -> bf16 MFMA fragment order ----------
__global__ __launch_bounds__(256) void cvtXW(
    const float* __restrict__ q, const float* __restrict__ k, const float* __restrict__ v,
    const float* __restrict__ Wq, const float* __restrict__ Wk,
    const float* __restrict__ Wv, const float* __restrict__ Wo,
    unsigned short* __restrict__ Xq, unsigned short* __restrict__ Xk, unsigned short* __restrict__ Xv,
    unsigned short* __restrict__ Wp)
{
  const int z = blockIdx.z;
  const int wave = threadIdx.x>>6, lane = threadIdx.x&63;
  const int l31 = lane&31, hi = lane>>5;
  const float* S;
  unsigned short* dst;
  int g;
  if (z < 3){
    S = (z==0)? q : (z==1)? k : v;
    unsigned short* D = (z==0)? Xq : (z==1)? Xk : Xv;
    g = blockIdx.x;                       // 0..127
    dst = D + (size_t)(g*64 + wave*16)*512 + lane*8;
  } else {
    const int wz = blockIdx.x>>5, gg = blockIdx.x&31;
    S = (wz==0)? Wq : (wz==1)? Wk : (wz==2)? Wv : Wo;
    g = gg;
    dst = Wp + (size_t)((wz*32 + gg)*64 + wave*16)*512 + lane*8;
  }
  const float* src = S + (size_t)(g*32 + l31)*DMODEL + 8*hi + 256*wave;
  #pragma unroll
  for (int i=0;i<16;i++)
    *(ushort8v*)(dst + (size_t)i*512) = cvt8(src + 16*i);
}

// ---------- A packer (bf16): Am[q32][kt][w][lane][8] = bf16(A[k][q]) ----------
__global__ __launch_bounds__(256) void cvtA(const float* __restrict__ A,
                                            unsigned short* __restrict__ Am){
  const int tid  = threadIdx.x;
  const int lane = tid&63, l31 = lane&31, hi = lane>>5;
  const int q32  = blockIdx.x;                 // 0..63
  const int kt   = blockIdx.y*4 + (tid>>6);    // 0..31
  const int q    = q32*32 + l31;

  unsigned short out8[4][8];
  #pragma unroll
  for (int fi=0; fi<2; fi++){
    #pragma unroll
    for (int mm=0; mm<4; mm++){
      #pragma unroll
      for (int j=0; j<4; j++){
        const int k = kt*64 + 32*fi + 8*mm + 4*hi + j;
        out8[fi*2 + (mm>>1)][(mm&1)*4 + j] = f2b(A[(size_t)k*SEQ + q]);
      }
    }
  }
  unsigned short* dst = Am + ((size_t)(q32*32 + kt)*4)*512 + lane*8;
  #pragma unroll
  for (int w=0; w<4; w++)
    *(ushort8v*)(dst + (size_t)w*512) = *(const ushort8v*)out8[w];
}

// ---------- fused q/k/v projection: m97-structure fragment GEMM ----------
// 128x128 tile, BK=64, single 32KB LDS buffer staged via global_load_lds
// (packed layouts are already lane*16B-linear -> native gload pattern).
// 2 barriers per K-step; 3 blocks/CU co-resident hide the drain (m114).
__global__ __launch_bounds__(256,3) void proj_qkv(
    const unsigned short* __restrict__ Xq, const unsigned short* __restrict__ Xk, const unsigned short* __restrict__ Xv,
    const unsigned short* __restrict__ Wp,
    const float* __restrict__ bq, const float* __restrict__ bk, const float* __restrict__ bv,
    unsigned short* __restrict__ qh, unsigned short* __restrict__ Kp, unsigned short* __restrict__ Vp)
{
  const int z = blockIdx.z;
  const unsigned short* X = (z==0)? Xq : (z==1)? Xk : Xv;
  const unsigned short* W = Wp + (size_t)z*1048576;
  const float* bias = (z==0)? bq : (z==1)? bk : bv;
  const float alpha = (z==0)? 0.125f : 1.0f;   // fold 1/sqrt(DK) into qh

  const int orig = blockIdx.y*8 + blockIdx.x;
  const int virt = (orig&7)*32 + (orig>>3);
  const int bx = virt&7, by = virt>>3;
  const int mb = by*128, nb = bx*128;

  const int tid = threadIdx.x;
  const int lane = tid&63, wave = tid>>6;
  const int wr = wave>>1, wc = wave&1, l31 = lane&31, hi = lane>>5;
  f32x16 acc[2][2] = {};

  // LDS: X chunks 0..15 at [0,16KB), W chunks 0..15 at [16KB,32KB)
  // chunk cc -> (m32 = cc>>2, s0 = cc&3), each chunk = 512 shorts (1KB)
  __shared__ unsigned short SM[16384];

  // staging roles: waves 0,1 stage X chunks {8w..8w+7}; waves 2,3 stage W
  const unsigned short* gsrc = (wave<2)
      ? X + (size_t)(mb>>5)*32768 + lane*8
      : W + (size_t)(nb>>5)*32768 + lane*8;
  const int cbase = (wave&1)*8;
  unsigned short* ldst = SM + ((wave<2)? 0 : 8192) + cbase*512 + 0;

  #pragma unroll 1
  for (int kb=0; kb<16; kb++){
    #pragma unroll
    for (int c=0;c<8;c++){
      const int cc = cbase + c;          // 0..15
      const int m32 = cc>>2, s0 = cc&3;
      GLOAD16(gsrc + (size_t)m32*32768 + (size_t)(kb*4+s0)*512, ldst + c*512);
    }
    __syncthreads();
    #pragma unroll
    for (int s0=0;s0<4;s0++){
      bf16x8 a0 = *(const bf16x8*)(SM + (8*wr +     s0)*512 + lane*8);
      bf16x8 a1 = *(const bf16x8*)(SM + (8*wr + 4 + s0)*512 + lane*8);
      bf16x8 b0 = *(const bf16x8*)(SM + 8192 + (8*wc +     s0)*512 + lane*8);
      bf16x8 b1 = *(const bf16x8*)(SM + 8192 + (8*wc + 4 + s0)*512 + lane*8);
      acc[0][0] = mfma32(a0,b0,acc[0][0]);
      acc[0][1] = mfma32(a0,b1,acc[0][1]);
      acc[1][0] = mfma32(a1,b0,acc[1][0]);
      acc[1][1] = mfma32(a1,b1,acc[1][1]);
    }
    __syncthreads();
  }

  #pragma unroll
  for (int fj=0; fj<2; fj++){
    const int e = nb + 64*wc + 32*fj + l31;
    const float bv_ = bias[e];
    const int hh = e>>6, dk = e&63;
    #pragma unroll
    for (int fi=0; fi<2; fi++){
      #pragma unroll
      for (int r=0;r<16;r++){
        const int i = mb + 64*wr + 32*fi + (r&3) + 8*(r>>2) + 4*hi;
        const int bb = i>>11, ss = i&(SEQ-1);
        const int bhh = bb*NHEAD + hh;
        const unsigned short val = f2b((acc[fi][fj][r] + bv_)*alpha);
        if (z==0){
          qh[((size_t)bhh*SEQ + ss)*DHEAD + dk] = val;
        } else if (z==1){
          const size_t addr = (((size_t)(bhh*64 + (ss>>5))*4 + (dk>>4))*64
                               + ((dk>>3)&1)*32 + (ss&31))*8 + (dk&7);
          Kp[addr] = val;
        } else {
          const size_t addr = ((((size_t)(bhh*32 + (ss>>6))*4 + ((ss>>4)&3))*2
                               + (dk>>5))*64 + ((ss>>3)&1)*32 + (dk&31))*8 + (ss&7);
          Vp[addr] = val;
        }
      }
    }
  }
}

// ---------- fused masked attention: x = (Qh Kh^T ∘ A^T) Vh ----------
// R12 structure + T4 counted vmcnt: raw s_barrier pairs, loads stay in flight
// across barriers (never drain to 0 in the main loop).
__global__ __launch_bounds__(512,4) void attn(
    const unsigned short* __restrict__ qh, const unsigned short* __restrict__ Kp,
    const unsigned short* __restrict__ Vp, const unsigned short* __restrict__ Am,
    unsigned short* __restrict__ xp)
{
  const int orig = blockIdx.y*16 + blockIdx.x;
  const int xcd = orig&7, within = orig>>3;   // within 0..63
  const int bh   = xcd*4 + (within>>4);       // 0..31
  const int qblk = within&15;                 // 0..15 (128 q-rows each)

  const int tid  = threadIdx.x;
  const int lane = tid&63, wave = tid>>6;     // wave 0..7
  const int qsub = wave&3, khalf = wave>>2;
  const int l31 = lane&31, hi = lane>>5;

  const int q32  = qblk*4 + qsub;
  const int qrow = q32*32 + l31;
  const unsigned short* qp = qh + ((size_t)bh*SEQ + qrow)*DHEAD;
  bf16x8 Qf[4];
  #pragma unroll
  for (int t=0;t<4;t++) Qf[t] = *(const bf16x8*)(qp + 16*t + 8*hi);

  f32x16 xacc[2] = {};

  const unsigned short* kpb = Kp + (size_t)bh*131072 + lane*8;   // [kt][frag][lane][8]
  const unsigned short* vpb = Vp + (size_t)bh*131072 + lane*8;
  const unsigned short* apb = Am + (size_t)q32*65536 + lane*8;   // [kt][w][lane][8]

  // staging: [buf][16 frags (K 0..7 | V 8..15)][512 shorts] = 32 KB;
  // reused post-loop as float Red[4][64][33] = 33792 B
  __shared__ float SMEMf[8448];
  unsigned short* smem = (unsigned short*)SMEMf;

  const unsigned short* gsb = ((wave<4)? kpb : vpb);
  const int fo = (wave&3)*2;                       // fragment pair within K or V
  const int dof = ((wave<4)? 0 : 4096) + fo*512;   // LDS dest offset (shorts)

  ushort8v Aa[2], Ab[2];

  // per tile per wave: 4 gload_lds + 2 A reg-loads = 6 vmem ops
  #define STAGE(BUF, KT) { \
    const unsigned short* _g = gsb + (size_t)(KT)*4096 + (size_t)fo*512; \
    GLOAD16(_g,       smem + (BUF)*8192 + dof); \
    GLOAD16(_g + 512, smem + (BUF)*8192 + dof + 512); }

  #define LOADA(DST, KT) { \
    const unsigned short* _ap = apb + (size_t)(KT)*2048 + (size_t)(khalf*2)*512; \
    DST[0] = *(const ushort8v*)(_ap); \
    DST[1] = *(const ushort8v*)(_ap + 512); }

  // prologue: tiles 0 and 1 in flight (12 vmem ops)
  STAGE(0, 0);  LOADA(Aa, 0);
  STAGE(1, 1);  LOADA(Ab, 1);

  // ITER: wait own tile-T ops (counted, NOT 0) -> barrier -> compute ->
  //       barrier -> stage tile T+2 (if DOSTAGE). Loads for T+1 stay in flight.
  #define ITER(T, BUF, AR, VM, DOSTAGE) { \
    asm volatile("s_waitcnt vmcnt(" VM ")" ::: "memory"); \
    __builtin_amdgcn_sched_barrier(0); \
    __builtin_amdgcn_s_barrier(); \
    __builtin_amdgcn_sched_barrier(0); \
    unsigned int wv[4], xv[4]; \
    { \
      f32x16 sacc = {}; \
      _Pragma("unroll") \
      for (int s=0;s<4;s++){ \
        bf16x8 kf = *(const bf16x8*)(smem + (BUF)*8192 + (khalf*4+s)*512 + lane*8); \
        sacc = mfma32(kf, Qf[s], sacc); \
      } \
      ushort8v a80 = AR[0], a81 = AR[1]; \
      _Pragma("unroll") \
      for (int mm=0; mm<4; mm++){ \
        const int b0 = (mm&1)*4, rb2 = 4*mm; \
        float p0 = sacc[rb2+0]*((mm>>1)? b2f(a81[b0+0]) : b2f(a80[b0+0])); \
        float p1 = sacc[rb2+1]*((mm>>1)? b2f(a81[b0+1]) : b2f(a80[b0+1])); \
        float p2 = sacc[rb2+2]*((mm>>1)? b2f(a81[b0+2]) : b2f(a80[b0+2])); \
        float p3 = sacc[rb2+3]*((mm>>1)? b2f(a81[b0+3]) : b2f(a80[b0+3])); \
        asm("v_cvt_pk_bf16_f32 %0, %1, %2" : "=v"(wv[mm]) : "v"(p0), "v"(p1)); \
        asm("v_cvt_pk_bf16_f32 %0, %1, %2" : "=v"(xv[mm]) : "v"(p2), "v"(p3)); \
      } \
    } \
    __builtin_amdgcn_s_setprio(1); \
    _Pragma("unroll") \
    for (int sl=0; sl<2; sl++){ \
      const int s2 = 2*khalf + sl; \
      uint2v rw = __builtin_amdgcn_permlane32_swap(wv[2*sl], wv[2*sl+1], false, false); \
      uint2v rx = __builtin_amdgcn_permlane32_swap(xv[2*sl], xv[2*sl+1], false, false); \
      int4v av; av.x = (int)rw[0]; av.y = (int)rx[0]; av.z = (int)rw[1]; av.w = (int)rx[1]; \
      bf16x8 pa = __builtin_bit_cast(bf16x8, av); \
      bf16x8 v0 = *(const bf16x8*)(smem + (BUF)*8192 + 4096 + (s2*2+0)*512 + lane*8); \
      bf16x8 v1 = *(const bf16x8*)(smem + (BUF)*8192 + 4096 + (s2*2+1)*512 + lane*8); \
      xacc[0] = mfma32(pa, v0, xacc[0]); \
      xacc[1] = mfma32(pa, v1, xacc[1]); \
    } \
    __builtin_amdgcn_s_setprio(0); \
    __builtin_amdgcn_sched_barrier(0); \
    __builtin_amdgcn_s_barrier(); \
    __builtin_amdgcn_sched_barrier(0); \
    if (DOSTAGE){ \
      STAGE(BUF, (T)+2); \
      LOADA(AR, (T)+2); \
    } }

  // t = 0..29: full pipeline (stages t+2 = 2..31, no wraparound)
  #pragma unroll 1
  for (int tt=0; tt<15; tt++){
    const int t0 = 2*tt, t1 = 2*tt+1;
    ITER(t0, 0, Aa, "6", 1);
    ITER(t1, 1, Ab, "6", 1);
  }
  // tail: t=30 (nothing more to stage), t=31 (drain)
  ITER(30, 0, Aa, "6", 0);
  ITER(31, 1, Ab, "0", 0);
  #undef ITER
  #undef STAGE
  #undef LOADA

  // cross-khalf reduction through the (now dead) staging LDS
  float* red = SMEMf;   // [4][64][33]
  __syncthreads();
  if (khalf==1){
    #pragma unroll
    for (int j=0;j<2;j++)
      #pragma unroll
      for (int r=0;r<16;r++)
        red[((qsub*64 + lane)*33) + 16*j + r] = xacc[j][r];
  }
  __syncthreads();
  if (khalf==0){
    #pragma unroll
    for (int j=0;j<2;j++)
      #pragma unroll
      for (int r=0;r<16;r++)
        xacc[j][r] += red[((qsub*64 + lane)*33) + 16*j + r];
    const int b = bh>>4, h = bh&15;
    #pragma unroll
    for (int fj=0; fj<2; fj++){
      const int scol = h*4 + fj*2 + (l31>>4);
      const int lpart = ((l31>>3)&1)*32;
      const int epart = l31&7;
      #pragma unroll
      for (int r=0;r<16;r++){
        const int qq = q32*32 + (r&3) + 8*(r>>2) + 4*hi;
        const int row = b*SEQ + qq;
        const size_t addr = ((size_t)(row>>5)*64 + scol)*512 + (lpart + (row&31))*8 + epart;
        xp[addr] = f2b(xacc[fj][r]);
      }
    }
  }
}

// ---------- output projection: 128x128 fragment GEMM, 8-wave K-split, fp32 out ----------
// (K-split valid here: grid = 256 blocks = 1/CU, LDS doesn't cut residency.)
__global__ __launch_bounds__(512,2) void oproj(
    const unsigned short* __restrict__ Xp, const unsigned short* __restrict__ Wop,
    const float* __restrict__ bo, float* __restrict__ out)
{
  const int orig = blockIdx.y*8 + blockIdx.x;
  const int virt = (orig&7)*32 + (orig>>3);
  const int bx = virt&7, by = virt>>3;
  const int mb = by*128, nb = bx*128;

  const int tid = threadIdx.x;
  const int lane = tid&63, wave = tid>>6;          // 0..7
  const int wc = wave&1, wr = (wave>>1)&1, ks = wave>>2;
  const int l31 = lane&31, hi = lane>>5;
  f32x16 acc[2][2] = {};

  const unsigned short* a0p = Xp  + (size_t)((mb>>5) + 2*wr)*32768 + lane*8;
  const unsigned short* a1p = a0p + 32768;
  const unsigned short* b0p = Wop + (size_t)((nb>>5) + 2*wc)*32768 + lane*8;
  const unsigned short* b1p = b0p + 32768;

  const int sbase = ks*32;
  #pragma unroll 8
  for (int s0=0; s0<32; s0++){
    const int s = sbase + s0;
    bf16x8 a0 = *(const bf16x8*)(a0p + (size_t)s*512);
    bf16x8 a1 = *(const bf16x8*)(a1p + (size_t)s*512);
    bf16x8 b0 = *(const bf16x8*)(b0p + (size_t)s*512);
    bf16x8 b1 = *(const bf16x8*)(b1p + (size_t)s*512);
    acc[0][0] = mfma32(a0,b0,acc[0][0]);
    acc[0][1] = mfma32(a0,b1,acc[0][1]);
    acc[1][0] = mfma32(a1,b0,acc[1][0]);
    acc[1][1] = mfma32(a1,b1,acc[1][1]);
  }

  // cross-ks reduction: ks=1 waves deposit, ks=0 waves add + store
  __shared__ float red[4][64][65];     // 66560 B, stride 65 -> conflict-free
  if (ks==1){
    #pragma unroll
    for (int fi=0; fi<2; fi++)
      #pragma unroll
      for (int fj=0; fj<2; fj++)
        #pragma unroll
        for (int r=0;r<16;r++)
          red[wr*2+wc][lane][(fi*2+fj)*16 + r] = acc[fi][fj][r];
  }
  __syncthreads();
  if (ks==0){
    #pragma unroll
    for (int fi=0; fi<2; fi++)
      #pragma unroll
      for (int fj=0; fj<2; fj++)
        #pragma unroll
        for (int r=0;r<16;r++)
          acc[fi][fj][r] += red[wr*2+wc][lane][(fi*2+fj)*16 + r];
    #pragma unroll
    for (int fj=0; fj<2; fj++){
      const int e = nb + 64*wc + 32*fj + l31;
      const float bv_ = bo[e];
      #pragma unroll
      for (int fi=0; fi<2; fi++){
        #pragma unroll
        for (int r=0;r<16;r++){
          const int i = mb + 64*wr + 32*fi + (r&3) + 8*(r>>2) + 4*hi;
          out[(size_t)i*DMODEL + e] = acc[fi][fj][r] + bv_;
        }
      }
    }
  }
}

extern "C" void kernel_launch(void* const* d_in, const int* in_sizes, int n_in,
                              void* d_out, int out_size, void* d_ws, size_t ws_size,
                              hipStream_t stream)
{
  const float* q  = (const float*)d_in[0];
  const float* k  = (const float*)d_in[1];
  const float* v  = (const float*)d_in[2];
  const float* A  = (const float*)d_in[3];
  const float* Wq = (const float*)d_in[4];
  const float* bq = (const float*)d_in[5];
  const float* Wk = (const float*)d_in[6];
  const float* bk = (const float*)d_in[7];
  const float* Wv = (const float*)d_in[8];
  const float* bv = (const float*)d_in[9];
  const float* Wo = (const float*)d_in[10];
  const float* bo = (const float*)d_in[11];
  float* out = (float*)d_out;

  // ws (bf16 elems): qh, Kp, Vp, xb, Wp -> 40MB. d_out as scratch:
  //   phase1: Xqp [0,8MB), Xkp [8,16MB)   (consumed by proj)
  //   phase2: Am bf16 [0,8MB)             (written by cvtA after proj, read by attn)
  //   phase3: final fp32 out              (oproj)
  unsigned short* ws = (unsigned short*)d_ws;
  const size_t NE = (size_t)NBATCH*SEQ*DMODEL;   // 4M elements
  unsigned short* qh  = ws;
  unsigned short* Kp  = qh + NE;
  unsigned short* Vp  = Kp + NE;
  unsigned short* xb  = Vp + NE;                 // Xvp before attn, packed-x after
  unsigned short* Wp  = xb + NE;                 // 4 packed weight matrices
  unsigned short* Xqp = (unsigned short*)d_out;
  unsigned short* Xkp = Xqp + NE;
  unsigned short* Am  = (unsigned short*)d_out;  // bf16 2048x2048 = 8MB
  unsigned short* Xvp = xb;

  cvtXW<<<dim3(128, 1, 4), 256, 0, stream>>>(q, k, v, Wq, Wk, Wv, Wo,
                                             Xqp, Xkp, Xvp, Wp);
  proj_qkv<<<dim3(8, 32, 3), 256, 0, stream>>>(
      Xqp, Xkp, Xvp, Wp, bq, bk, bv, qh, Kp, Vp);
  cvtA<<<dim3(64, 8), 256, 0, stream>>>(A, Am);
  attn<<<dim3(16, 32), 512, 0, stream>>>(qh, Kp, Vp, Am, xb);
  oproj<<<dim3(8, 32), 512, 0, stream>>>(xb, Wp + (size_t)3*1048576, bo, out);
}